// Round 3
// baseline (305.548 us; speedup 1.0000x reference)
//
#include <hip/hip_runtime.h>
#include <hip/hip_fp16.h>
#include <cstdint>
#include <cstddef>

typedef _Float16 f16;
typedef __attribute__((ext_vector_type(4))) _Float16 f16x4;
typedef __attribute__((ext_vector_type(8))) _Float16 f16x8;
typedef __attribute__((ext_vector_type(4))) float f32x4;

#define C_INV_SQRT2 0.70710678118654752440f

__device__ __forceinline__ void gld_lds16(const void* g, void* l) {
  __builtin_amdgcn_global_load_lds((const __attribute__((address_space(1))) void*)g,
                                   (__attribute__((address_space(3))) void*)l, 16, 0, 0);
}

// ---------------- conversion kernels ----------------
__global__ __launch_bounds__(256) void cvt_f32_f16_k(const float* __restrict__ in,
                                                     f16* __restrict__ out, int n4) {
  int i = blockIdx.x * 256 + threadIdx.x;
  if (i >= n4) return;
  const float4 x = ((const float4*)in)[i];
  f16x4 y;
  y.x = (f16)x.x; y.y = (f16)x.y; y.z = (f16)x.z; y.w = (f16)x.w;
  ((f16x4*)out)[i] = y;
}

// pack W_qkv rows {0..1023} and {2048..3071} into Wo[2048][1024] f16; same for bias
__global__ __launch_bounds__(256) void pack_wqv_k(const float* __restrict__ W,
                                                  const float* __restrict__ b,
                                                  f16* __restrict__ Wo,
                                                  float* __restrict__ bo) {
  int i = blockIdx.x * 256 + threadIdx.x;
  int n = i >> 8;
  int c = (i & 255) * 4;
  int sn = (n < 1024) ? n : (n + 1024);
  const float4 x = *(const float4*)(W + (size_t)sn * 1024 + c);
  f16x4 y; y.x = (f16)x.x; y.y = (f16)x.y; y.z = (f16)x.z; y.w = (f16)x.w;
  *(f16x4*)(Wo + (size_t)n * 1024 + c) = y;
  if (i < 2048) bo[i] = b[(i < 1024) ? i : (i + 1024)];
}

// ---- 256x256 GEMM, 4-deep sub-tile pipeline: C[M,N] = A[M,K]*B[N,K]^T + bias ----
// 512 threads = 8 waves (2M x 4N); per-wave output 128(M) x 64(N).
// Sub-tile = BK=32 K-slice; 4 LDS buffers (4 x 32 KiB = 128 KiB).
// Phase s: STAGE(s+3) -> vmcnt(12) [sub-tile s complete, 3 in flight]
//          -> barrier -> 12 ds_read_b128 -> setprio(1) 32 MFMA setprio(0) -> barrier.
// LDS chunk-XOR swizzle: chunk' = chunk ^ ((row>>1)&3)  (both-sides, rule 21).
// T1 bijective XCD swizzle (nwg % 8 == 0).

#define STAGE4(bufi, k0)                          \
  {                                               \
    f16* LA = &lds[bufi][0][0];                   \
    f16* LB = &lds[bufi][1][0];                   \
    gld_lds16(pGA0 + (k0), LA + dst0);            \
    gld_lds16(pGA1 + (k0), LA + dst1);            \
    gld_lds16(pGB0 + (k0), LB + dst0);            \
    gld_lds16(pGB1 + (k0), LB + dst1);            \
  }

template <typename CT>
__global__ __launch_bounds__(512, 2) void gemm256_k(const f16* __restrict__ A,
                                                    const f16* __restrict__ B,
                                                    const float* __restrict__ bias,
                                                    CT* __restrict__ C,
                                                    int M, int N, int K, int nbx) {
  __shared__ f16 lds[4][2][256 * 32];  // [buf][A/B][256 rows x 32 f16] = 128 KiB
  const int t = threadIdx.x;
  const int w = t >> 6, l = t & 63;
  const int wm = w >> 2, wn = w & 3;  // 2 x 4 wave grid
  const int hi = l >> 4, lo = l & 15;

  // T1: bijective XCD swizzle
  const int nwg = gridDim.x;
  const int cpx = nwg >> 3;
  const int bid = blockIdx.x;
  const int nid = (bid & 7) * cpx + (bid >> 3);
  const int by = nid / nbx, bx = nid - by * nbx;
  const int m0 = by * 256, n0 = bx * 256;

  const f16* GA = A + (size_t)m0 * K;
  const f16* GB = B + (size_t)n0 * K;

  // staging: thread covers 16B slots u = i*512 + t (i=0,1) of a [256 row][4 chunk] plane
  // slot u holds global (row = u>>2, chunk = (u&3) ^ ((u>>3)&3))  [inverse-swizzled src]
  int rowS[2], chS[2];
#pragma unroll
  for (int i = 0; i < 2; i++) {
    const int u = i * 512 + t;
    rowS[i] = u >> 2;
    chS[i] = (u & 3) ^ ((u >> 3) & 3);
  }
  const f16* pGA0 = GA + (size_t)rowS[0] * K + chS[0] * 8;
  const f16* pGA1 = GA + (size_t)rowS[1] * K + chS[1] * 8;
  const f16* pGB0 = GB + (size_t)rowS[0] * K + chS[0] * 8;
  const f16* pGB1 = GB + (size_t)rowS[1] * K + chS[1] * 8;
  const int dst0 = (0 * 512 + w * 64) * 8;  // wave-uniform LDS dest (f16 units)
  const int dst1 = (1 * 512 + w * 64) * 8;

  // read-side swizzled fragment offsets (f16 units within one [256][32] plane)
  int offA[8], offB[4];
#pragma unroll
  for (int mi = 0; mi < 8; mi++) {
    const int r = wm * 128 + mi * 16 + lo;
    offA[mi] = r * 32 + ((hi ^ ((r >> 1) & 3)) << 3);
  }
#pragma unroll
  for (int nj = 0; nj < 4; nj++) {
    const int r = wn * 64 + nj * 16 + lo;
    offB[nj] = r * 32 + ((hi ^ ((r >> 1) & 3)) << 3);
  }

  f32x4 acc[8][4] = {};
  const int NS = K >> 5;  // sub-tiles of K=32

  STAGE4(0, 0);
  STAGE4(1, 32);
  STAGE4(2, 64);

  for (int s = 0; s < NS; ++s) {
    const int cur = s & 3;
    if (s < NS - 3) {
      STAGE4((s + 3) & 3, (s + 3) * 32);
      asm volatile("s_waitcnt vmcnt(12)" ::: "memory");
    } else if (s == NS - 3) {
      asm volatile("s_waitcnt vmcnt(8)" ::: "memory");
    } else if (s == NS - 2) {
      asm volatile("s_waitcnt vmcnt(4)" ::: "memory");
    } else {
      asm volatile("s_waitcnt vmcnt(0)" ::: "memory");
    }
    __builtin_amdgcn_s_barrier();
    __builtin_amdgcn_sched_barrier(0);
    const f16* pA = &lds[cur][0][0];
    const f16* pB = &lds[cur][1][0];
    f16x8 af[8], bf[4];
#pragma unroll
    for (int mi = 0; mi < 8; mi++) af[mi] = *(const f16x8*)(pA + offA[mi]);
#pragma unroll
    for (int nj = 0; nj < 4; nj++) bf[nj] = *(const f16x8*)(pB + offB[nj]);
    __builtin_amdgcn_s_setprio(1);
#pragma unroll
    for (int mi = 0; mi < 8; mi++)
#pragma unroll
      for (int nj = 0; nj < 4; nj++)
        acc[mi][nj] =
            __builtin_amdgcn_mfma_f32_16x16x32_f16(af[mi], bf[nj], acc[mi][nj], 0, 0, 0);
    __builtin_amdgcn_s_setprio(0);
    __builtin_amdgcn_sched_barrier(0);
    __builtin_amdgcn_s_barrier();
  }

  // epilogue: C/D layout col = lane&15, row = (lane>>4)*4 + reg
#pragma unroll
  for (int mi = 0; mi < 8; mi++) {
#pragma unroll
    for (int nj = 0; nj < 4; nj++) {
      const int col = n0 + wn * 64 + nj * 16 + lo;
      const float bb = bias[col];
      const size_t base = (size_t)(m0 + wm * 128 + mi * 16 + hi * 4) * N + col;
#pragma unroll
      for (int r = 0; r < 4; r++) C[base + (size_t)r * N] = (CT)(acc[mi][nj][r] + bb);
    }
  }
}

// ---------------- fused wavelet middle (vectorized f16x4 loads) ----------------
// qv: [32768][2048] f16 (cols 0..1023 = q, 1024..2047 = v), out: [32768][1024] f16
__global__ __launch_bounds__(256) void dwt_middle_k(const f16* __restrict__ qv,
                                                    const float* __restrict__ wq,
                                                    const float* __restrict__ wv,
                                                    f16* __restrict__ out) {
  const int g = blockIdx.x;           // row-group (8 rows), 0..4095
  const int d0 = threadIdx.x * 4;     // 4 consecutive d per thread
  const size_t m0 = (size_t)g * 8;

  f16x4 qr[8], vr[8], o[8];
#pragma unroll
  for (int i = 0; i < 8; i++) {
    qr[i] = *(const f16x4*)(qv + (m0 + i) * 2048 + d0);
    vr[i] = *(const f16x4*)(qv + (m0 + i) * 2048 + 1024 + d0);
  }
  const float c = C_INV_SQRT2;
#pragma unroll
  for (int dd = 0; dd < 4; dd++) {
    const int d = d0 + dd;
    const int h = d >> 6, dh = d & 63;
    float q[8], v[8];
#pragma unroll
    for (int i = 0; i < 8; i++) { q[i] = (float)qr[i][dd]; v[i] = (float)vr[i][dd]; }

    float qa1[4], qd1[4], va1[4], vd1[4];
#pragma unroll
    for (int i = 0; i < 4; i++) {
      qd1[i] = (q[2 * i] - q[2 * i + 1]) * c;
      qa1[i] = (q[2 * i] + q[2 * i + 1]) * c;
      vd1[i] = (v[2 * i] - v[2 * i + 1]) * c;
      va1[i] = (v[2 * i] + v[2 * i + 1]) * c;
    }
    float qa2[2], qd2[2], va2[2], vd2[2];
#pragma unroll
    for (int j = 0; j < 2; j++) {
      qd2[j] = (qa1[2 * j] - qa1[2 * j + 1]) * c;
      qa2[j] = (qa1[2 * j] + qa1[2 * j + 1]) * c;
      vd2[j] = (va1[2 * j] - va1[2 * j + 1]) * c;
      va2[j] = (va1[2 * j] + va1[2 * j + 1]) * c;
    }
    const float qd3 = (qa2[0] - qa2[1]) * c, qa3 = (qa2[0] + qa2[1]) * c;
    const float vd3 = (va2[0] - va2[1]) * c, va3 = (va2[0] + va2[1]) * c;

    const int wb = h * 192 + dh;
    const float wq0 = wq[wb], wq1 = wq[wb + 64], wq2 = wq[wb + 128];
    const float wv0 = wv[wb], wv1 = wv[wb + 64], wv2 = wv[wb + 128];

    const float pa = (qa3 * wq0) * (va3 * wv0);
    const float pd3 = (qd3 * wq1) * (vd3 * wv1);
    float pd2[2], pd1[4];
#pragma unroll
    for (int j = 0; j < 2; j++) pd2[j] = (qd2[j] * wq2) * (vd2[j] * wv2);
#pragma unroll
    for (int i = 0; i < 4; i++) pd1[i] = qd1[i] * vd1[i];

    float s2[2], s1[4];
    s2[0] = (pa + pd3) * c;
    s2[1] = (pa - pd3) * c;
#pragma unroll
    for (int j = 0; j < 2; j++) {
      s1[2 * j] = (s2[j] + pd2[j]) * c;
      s1[2 * j + 1] = (s2[j] - pd2[j]) * c;
    }
#pragma unroll
    for (int i = 0; i < 4; i++) {
      o[2 * i][dd] = (f16)((s1[i] + pd1[i]) * c);
      o[2 * i + 1][dd] = (f16)((s1[i] - pd1[i]) * c);
    }
  }
#pragma unroll
  for (int i = 0; i < 8; i++) *(f16x4*)(out + (m0 + i) * 1024 + d0) = o[i];
}

// ---------------- launch ----------------
extern "C" void kernel_launch(void* const* d_in, const int* in_sizes, int n_in,
                              void* d_out, int out_size, void* d_ws, size_t ws_size,
                              hipStream_t stream) {
  (void)in_sizes; (void)n_in; (void)out_size; (void)ws_size;
  const float* query = (const float*)d_in[0];
  const float* W_qkv = (const float*)d_in[1];
  const float* b_qkv = (const float*)d_in[2];
  const float* W_out = (const float*)d_in[3];
  const float* b_out = (const float*)d_in[4];
  const float* wq = (const float*)d_in[5];
  const float* wv = (const float*)d_in[6];
  float* out = (float*)d_out;

  // workspace layout
  char* ws = (char*)d_ws;
  f16* qf16 = (f16*)ws;                                // 67,108,864 B (reused as a_f16)
  f16* Wqv = (f16*)(ws + 67108864);                    //  4,194,304 B
  float* bqv = (float*)(ws + 67108864 + 4194304);      //      8,192 B
  f16* Wout = (f16*)(ws + 67108864 + 4194304 + 8192);  //  2,097,152 B
  f16* qv = (f16*)d_out;  // qv intermediate lives in d_out (exactly out bytes)
  f16* a_f16 = qf16;      // alias: qf16 dead after GEMM1

  // 1. query -> f16
  cvt_f32_f16_k<<<dim3(8388608 / 256), dim3(256), 0, stream>>>(query, qf16, 8388608);
  // 2. pack W_qv + bias
  pack_wqv_k<<<dim3(2048), dim3(256), 0, stream>>>(W_qkv, b_qkv, Wqv, bqv);
  // 3. W_out -> f16
  cvt_f32_f16_k<<<dim3(262144 / 256), dim3(256), 0, stream>>>(W_out, Wout, 262144);
  // 4. GEMM1: qv[32768,2048] = query_f16 * Wqv^T + bqv   (grid 8*128 = 1024 blocks)
  gemm256_k<f16><<<dim3((2048 / 256) * (32768 / 256)), dim3(512), 0, stream>>>(
      qf16, Wqv, bqv, qv, 32768, 2048, 1024, 2048 / 256);
  // 5. fused wavelet middle: a[32768,1024] f16
  dwt_middle_k<<<dim3(4096), dim3(256), 0, stream>>>(qv, wq, wv, a_f16);
  // 6. GEMM2: out = a * Wout^T + b_out (fp32)   (grid 4*128 = 512 blocks)
  gemm256_k<float><<<dim3((1024 / 256) * (32768 / 256)), dim3(512), 0, stream>>>(
      a_f16, Wout, b_out, out, 32768, 1024, 1024, 1024 / 256);
}

// Round 4
// 295.963 us; speedup vs baseline: 1.0324x; 1.0324x over previous
//
#include <hip/hip_runtime.h>
#include <hip/hip_fp16.h>
#include <cstdint>
#include <cstddef>

typedef _Float16 f16;
typedef __attribute__((ext_vector_type(4))) _Float16 f16x4;
typedef __attribute__((ext_vector_type(8))) _Float16 f16x8;
typedef __attribute__((ext_vector_type(4))) float f32x4;

#define C_INV_SQRT2 0.70710678118654752440f

__device__ __forceinline__ void gld_lds16(const void* g, void* l) {
  __builtin_amdgcn_global_load_lds((const __attribute__((address_space(1))) void*)g,
                                   (__attribute__((address_space(3))) void*)l, 16, 0, 0);
}

// ---------------- conversion kernels ----------------
__global__ __launch_bounds__(256) void cvt_f32_f16_k(const float* __restrict__ in,
                                                     f16* __restrict__ out, int n4) {
  int i = blockIdx.x * 256 + threadIdx.x;
  if (i >= n4) return;
  const float4 x = ((const float4*)in)[i];
  f16x4 y;
  y.x = (f16)x.x; y.y = (f16)x.y; y.z = (f16)x.z; y.w = (f16)x.w;
  ((f16x4*)out)[i] = y;
}

// pack W_qkv rows {0..1023} and {2048..3071} into Wo[2048][1024] f16; same for bias
__global__ __launch_bounds__(256) void pack_wqv_k(const float* __restrict__ W,
                                                  const float* __restrict__ b,
                                                  f16* __restrict__ Wo,
                                                  float* __restrict__ bo) {
  int i = blockIdx.x * 256 + threadIdx.x;
  int n = i >> 8;
  int c = (i & 255) * 4;
  int sn = (n < 1024) ? n : (n + 1024);
  const float4 x = *(const float4*)(W + (size_t)sn * 1024 + c);
  f16x4 y; y.x = (f16)x.x; y.y = (f16)x.y; y.z = (f16)x.z; y.w = (f16)x.w;
  *(f16x4*)(Wo + (size_t)n * 1024 + c) = y;
  if (i < 2048) bo[i] = b[(i < 1024) ? i : (i + 1024)];
}

// ---- 256x256 GEMM, 4-deep sub-tile pipeline, ONE barrier per segment ----
// C[M,N] = A[M,K]*B[N,K]^T + bias.  512 threads = 8 waves (2M x 4N);
// per-wave output 128(M) x 64(N).  Sub-tile = BK=32; 4 LDS buffers (128 KiB).
// Segment s: vmcnt(8) [stage(s) landed; s+1,s+2 in flight] -> barrier ->
//   issue 12 ds_read_b128 + STAGE(s+3) -> MFMA mh0 x16 -> MFMA mh1 x16
// (compiler inserts fine-grained lgkmcnt between reads and MFMAs; no
//  order-pinning fences inside the covered region).
// LDS chunk-XOR swizzle: chunk' = chunk ^ ((row>>1)&3)  (both-sides, rule 21).
// T1 bijective XCD swizzle (nwg % 8 == 0).

#define STAGE4(bufi, k0)                          \
  {                                               \
    f16* LA = &lds[bufi][0][0];                   \
    f16* LB = &lds[bufi][1][0];                   \
    gld_lds16(pGA0 + (k0), LA + dst0);            \
    gld_lds16(pGA1 + (k0), LA + dst1);            \
    gld_lds16(pGB0 + (k0), LB + dst0);            \
    gld_lds16(pGB1 + (k0), LB + dst1);            \
  }

template <typename CT>
__global__ __launch_bounds__(512, 2) void gemm256_k(const f16* __restrict__ A,
                                                    const f16* __restrict__ B,
                                                    const float* __restrict__ bias,
                                                    CT* __restrict__ C,
                                                    int M, int N, int K, int nbx) {
  __shared__ f16 lds[4][2][256 * 32];  // [buf][A/B][256 rows x 32 f16] = 128 KiB
  const int t = threadIdx.x;
  const int w = t >> 6, l = t & 63;
  const int wm = w >> 2, wn = w & 3;  // 2 x 4 wave grid
  const int hi = l >> 4, lo = l & 15;

  // T1: bijective XCD swizzle
  const int nwg = gridDim.x;
  const int cpx = nwg >> 3;
  const int bid = blockIdx.x;
  const int nid = (bid & 7) * cpx + (bid >> 3);
  const int by = nid / nbx, bx = nid - by * nbx;
  const int m0 = by * 256, n0 = bx * 256;

  const f16* GA = A + (size_t)m0 * K;
  const f16* GB = B + (size_t)n0 * K;

  // staging: thread covers 16B slots u = i*512 + t (i=0,1) of a [256 row][4 chunk] plane
  // slot u holds global (row = u>>2, chunk = (u&3) ^ ((u>>3)&3))  [inverse-swizzled src]
  int rowS[2], chS[2];
#pragma unroll
  for (int i = 0; i < 2; i++) {
    const int u = i * 512 + t;
    rowS[i] = u >> 2;
    chS[i] = (u & 3) ^ ((u >> 3) & 3);
  }
  const f16* pGA0 = GA + (size_t)rowS[0] * K + chS[0] * 8;
  const f16* pGA1 = GA + (size_t)rowS[1] * K + chS[1] * 8;
  const f16* pGB0 = GB + (size_t)rowS[0] * K + chS[0] * 8;
  const f16* pGB1 = GB + (size_t)rowS[1] * K + chS[1] * 8;
  const int dst0 = (0 * 512 + w * 64) * 8;  // wave-uniform LDS dest (f16 units)
  const int dst1 = (1 * 512 + w * 64) * 8;

  // read-side swizzled fragment offsets (f16 units within one [256][32] plane)
  int offA[8], offB[4];
#pragma unroll
  for (int mi = 0; mi < 8; mi++) {
    const int r = wm * 128 + mi * 16 + lo;
    offA[mi] = r * 32 + ((hi ^ ((r >> 1) & 3)) << 3);
  }
#pragma unroll
  for (int nj = 0; nj < 4; nj++) {
    const int r = wn * 64 + nj * 16 + lo;
    offB[nj] = r * 32 + ((hi ^ ((r >> 1) & 3)) << 3);
  }

  f32x4 acc[8][4] = {};
  const int NS = K >> 5;  // sub-tiles of K=32

  STAGE4(0, 0);
  STAGE4(1, 32);
  STAGE4(2, 64);

  for (int s = 0; s < NS; ++s) {
    const int cur = s & 3;
    // ensure stage(s) landed everywhere; keep newer stages in flight
    if (s <= NS - 3) {
      asm volatile("s_waitcnt vmcnt(8)" ::: "memory");
    } else if (s == NS - 2) {
      asm volatile("s_waitcnt vmcnt(4)" ::: "memory");
    } else {
      asm volatile("s_waitcnt vmcnt(0)" ::: "memory");
    }
    __builtin_amdgcn_sched_barrier(0);
    __builtin_amdgcn_s_barrier();
    __builtin_amdgcn_sched_barrier(0);

    const f16* pA = &lds[cur][0][0];
    const f16* pB = &lds[cur][1][0];
    f16x8 af[8], bf[4];
#pragma unroll
    for (int mi = 0; mi < 4; mi++) af[mi] = *(const f16x8*)(pA + offA[mi]);
#pragma unroll
    for (int nj = 0; nj < 4; nj++) bf[nj] = *(const f16x8*)(pB + offB[nj]);
#pragma unroll
    for (int mi = 4; mi < 8; mi++) af[mi] = *(const f16x8*)(pA + offA[mi]);

    if (s + 3 < NS) STAGE4((s + 3) & 3, (s + 3) * 32);

    __builtin_amdgcn_s_setprio(1);
#pragma unroll
    for (int mi = 0; mi < 4; mi++)
#pragma unroll
      for (int nj = 0; nj < 4; nj++)
        acc[mi][nj] =
            __builtin_amdgcn_mfma_f32_16x16x32_f16(af[mi], bf[nj], acc[mi][nj], 0, 0, 0);
#pragma unroll
    for (int mi = 4; mi < 8; mi++)
#pragma unroll
      for (int nj = 0; nj < 4; nj++)
        acc[mi][nj] =
            __builtin_amdgcn_mfma_f32_16x16x32_f16(af[mi], bf[nj], acc[mi][nj], 0, 0, 0);
    __builtin_amdgcn_s_setprio(0);
  }

  // epilogue: C/D layout col = lane&15, row = (lane>>4)*4 + reg
#pragma unroll
  for (int mi = 0; mi < 8; mi++) {
#pragma unroll
    for (int nj = 0; nj < 4; nj++) {
      const int col = n0 + wn * 64 + nj * 16 + lo;
      const float bb = bias[col];
      const size_t base = (size_t)(m0 + wm * 128 + mi * 16 + hi * 4) * N + col;
#pragma unroll
      for (int r = 0; r < 4; r++) C[base + (size_t)r * N] = (CT)(acc[mi][nj][r] + bb);
    }
  }
}

// ---------------- fused wavelet middle (vectorized f16x4 loads) ----------------
// qv: [32768][2048] f16 (cols 0..1023 = q, 1024..2047 = v), out: [32768][1024] f16
__global__ __launch_bounds__(256) void dwt_middle_k(const f16* __restrict__ qv,
                                                    const float* __restrict__ wq,
                                                    const float* __restrict__ wv,
                                                    f16* __restrict__ out) {
  const int g = blockIdx.x;           // row-group (8 rows), 0..4095
  const int d0 = threadIdx.x * 4;     // 4 consecutive d per thread
  const size_t m0 = (size_t)g * 8;

  f16x4 qr[8], vr[8], o[8];
#pragma unroll
  for (int i = 0; i < 8; i++) {
    qr[i] = *(const f16x4*)(qv + (m0 + i) * 2048 + d0);
    vr[i] = *(const f16x4*)(qv + (m0 + i) * 2048 + 1024 + d0);
  }
  const float c = C_INV_SQRT2;
#pragma unroll
  for (int dd = 0; dd < 4; dd++) {
    const int d = d0 + dd;
    const int h = d >> 6, dh = d & 63;
    float q[8], v[8];
#pragma unroll
    for (int i = 0; i < 8; i++) { q[i] = (float)qr[i][dd]; v[i] = (float)vr[i][dd]; }

    float qa1[4], qd1[4], va1[4], vd1[4];
#pragma unroll
    for (int i = 0; i < 4; i++) {
      qd1[i] = (q[2 * i] - q[2 * i + 1]) * c;
      qa1[i] = (q[2 * i] + q[2 * i + 1]) * c;
      vd1[i] = (v[2 * i] - v[2 * i + 1]) * c;
      va1[i] = (v[2 * i] + v[2 * i + 1]) * c;
    }
    float qa2[2], qd2[2], va2[2], vd2[2];
#pragma unroll
    for (int j = 0; j < 2; j++) {
      qd2[j] = (qa1[2 * j] - qa1[2 * j + 1]) * c;
      qa2[j] = (qa1[2 * j] + qa1[2 * j + 1]) * c;
      vd2[j] = (va1[2 * j] - va1[2 * j + 1]) * c;
      va2[j] = (va1[2 * j] + va1[2 * j + 1]) * c;
    }
    const float qd3 = (qa2[0] - qa2[1]) * c, qa3 = (qa2[0] + qa2[1]) * c;
    const float vd3 = (va2[0] - va2[1]) * c, va3 = (va2[0] + va2[1]) * c;

    const int wb = h * 192 + dh;
    const float wq0 = wq[wb], wq1 = wq[wb + 64], wq2 = wq[wb + 128];
    const float wv0 = wv[wb], wv1 = wv[wb + 64], wv2 = wv[wb + 128];

    const float pa = (qa3 * wq0) * (va3 * wv0);
    const float pd3 = (qd3 * wq1) * (vd3 * wv1);
    float pd2[2], pd1[4];
#pragma unroll
    for (int j = 0; j < 2; j++) pd2[j] = (qd2[j] * wq2) * (vd2[j] * wv2);
#pragma unroll
    for (int i = 0; i < 4; i++) pd1[i] = qd1[i] * vd1[i];

    float s2[2], s1[4];
    s2[0] = (pa + pd3) * c;
    s2[1] = (pa - pd3) * c;
#pragma unroll
    for (int j = 0; j < 2; j++) {
      s1[2 * j] = (s2[j] + pd2[j]) * c;
      s1[2 * j + 1] = (s2[j] - pd2[j]) * c;
    }
#pragma unroll
    for (int i = 0; i < 4; i++) {
      o[2 * i][dd] = (f16)((s1[i] + pd1[i]) * c);
      o[2 * i + 1][dd] = (f16)((s1[i] - pd1[i]) * c);
    }
  }
#pragma unroll
  for (int i = 0; i < 8; i++) *(f16x4*)(out + (m0 + i) * 1024 + d0) = o[i];
}

// ---------------- launch ----------------
extern "C" void kernel_launch(void* const* d_in, const int* in_sizes, int n_in,
                              void* d_out, int out_size, void* d_ws, size_t ws_size,
                              hipStream_t stream) {
  (void)in_sizes; (void)n_in; (void)out_size; (void)ws_size;
  const float* query = (const float*)d_in[0];
  const float* W_qkv = (const float*)d_in[1];
  const float* b_qkv = (const float*)d_in[2];
  const float* W_out = (const float*)d_in[3];
  const float* b_out = (const float*)d_in[4];
  const float* wq = (const float*)d_in[5];
  const float* wv = (const float*)d_in[6];
  float* out = (float*)d_out;

  // workspace layout
  char* ws = (char*)d_ws;
  f16* qf16 = (f16*)ws;                                // 67,108,864 B (reused as a_f16)
  f16* Wqv = (f16*)(ws + 67108864);                    //  4,194,304 B
  float* bqv = (float*)(ws + 67108864 + 4194304);      //      8,192 B
  f16* Wout = (f16*)(ws + 67108864 + 4194304 + 8192);  //  2,097,152 B
  f16* qv = (f16*)d_out;  // qv intermediate lives in d_out (exactly out bytes)
  f16* a_f16 = qf16;      // alias: qf16 dead after GEMM1

  // 1. query -> f16
  cvt_f32_f16_k<<<dim3(8388608 / 256), dim3(256), 0, stream>>>(query, qf16, 8388608);
  // 2. pack W_qv + bias
  pack_wqv_k<<<dim3(2048), dim3(256), 0, stream>>>(W_qkv, b_qkv, Wqv, bqv);
  // 3. W_out -> f16
  cvt_f32_f16_k<<<dim3(262144 / 256), dim3(256), 0, stream>>>(W_out, Wout, 262144);
  // 4. GEMM1: qv[32768,2048] = query_f16 * Wqv^T + bqv   (grid 8*128 = 1024 blocks)
  gemm256_k<f16><<<dim3((2048 / 256) * (32768 / 256)), dim3(512), 0, stream>>>(
      qf16, Wqv, bqv, qv, 32768, 2048, 1024, 2048 / 256);
  // 5. fused wavelet middle: a[32768,1024] f16
  dwt_middle_k<<<dim3(4096), dim3(256), 0, stream>>>(qv, wq, wv, a_f16);
  // 6. GEMM2: out = a * Wout^T + b_out (fp32)   (grid 4*128 = 512 blocks)
  gemm256_k<float><<<dim3((1024 / 256) * (32768 / 256)), dim3(512), 0, stream>>>(
      a_f16, Wout, b_out, out, 32768, 1024, 1024, 1024 / 256);
}